// Round 13
// baseline (365.289 us; speedup 1.0000x reference)
//
#include <hip/hip_runtime.h>
#include <hip/hip_bf16.h>

typedef __bf16 bf16x8 __attribute__((ext_vector_type(8)));
typedef float f32x4 __attribute__((ext_vector_type(4)));

#define HH 512
#define WW 512
#define NC 9
#define LDSB 42240        // A tile: 10 rows x 66 cols x 64B
#define W3_OFF 79104      // after B (42240 + 9*4096)
#define B3_OFF 81408

static __device__ __forceinline__ ushort f2bf(float x) {
  union { float f; unsigned u; } c; c.f = x;
  unsigned r = c.u + 0x7FFFu + ((c.u >> 16) & 1u);
  return (ushort)(r >> 16);
}

// ---------------- K1: proj GEMM: feat[1024,256] = hs[1024,768] @ pw[768,256] + pb ----------------
__global__ __launch_bounds__(256) void proj_gemm_kernel(
    const float* __restrict__ hs, const float* __restrict__ pw,
    const float* __restrict__ pb, float* __restrict__ feat) {
  __shared__ float As[16 * 132];
  __shared__ float4 Bs4[2048];
  int tid = threadIdx.x;
  int r0 = blockIdx.x * 16;
  int n0 = blockIdx.y * 64;
  int r = tid >> 4;
  int c4 = (tid & 15) << 2;
  float4 acc = *(const float4*)(pb + n0 + c4);
  for (int k0 = 0; k0 < 768; k0 += 128) {
    __syncthreads();
    #pragma unroll
    for (int i = 0; i < 8; ++i) {
      int idx = tid + i * 256;
      As[(idx >> 7) * 132 + (idx & 127)] =
          hs[(size_t)(r0 + (idx >> 7)) * 768 + k0 + (idx & 127)];
    }
    #pragma unroll
    for (int i = 0; i < 8; ++i) {
      int idx = tid + i * 256;
      Bs4[idx] = *(const float4*)(pw + (size_t)(k0 + (idx >> 4)) * 256 + n0 + ((idx & 15) << 2));
    }
    __syncthreads();
    const float* ar = As + r * 132;
    #pragma unroll 8
    for (int k = 0; k < 128; ++k) {
      float a = ar[k];
      float4 bv = Bs4[(k << 4) + (c4 >> 2)];
      acc.x = fmaf(a, bv.x, acc.x); acc.y = fmaf(a, bv.y, acc.y);
      acc.z = fmaf(a, bv.z, acc.z); acc.w = fmaf(a, bv.w, acc.w);
    }
  }
  *(float4*)(feat + (size_t)(r0 + r) * 256 + n0 + c4) = acc;
}

// ---------------- K2: winner map via atomic scatter ----------------
__global__ __launch_bounds__(64) void scatter_kernel(
    const int* __restrict__ bbox, const int* __restrict__ amask,
    int* __restrict__ winner) {
  int token = blockIdx.x;
  int b = token >> 9, s = token & 511;
  if (s == 0) return;
  const int* bb = bbox + (size_t)token * 4;
  int x1 = (bb[0] * 512) / 1000; if (x1 < 0) x1 = 0;
  int y1 = (bb[1] * 512) / 1000; if (y1 < 0) y1 = 0;
  int x2 = (bb[2] * 512) / 1000; if (x2 > 511) x2 = 511;
  int y2 = (bb[3] * 512) / 1000; if (y2 > 511) y2 = 511;
  if (amask[token] != 1 || x2 <= x1 || y2 <= y1) return;
  int lane = threadIdx.x;
  for (int yy = y1; yy < y2; ++yy) {
    int rowbase = (b << 18) + (yy << 9);
    for (int xx = x1 + lane; xx < x2; xx += 64)
      atomicMax(&winner[rowbase + xx], s);
  }
}

// ---------------- K2.4: w1r[ic][tap*128+oc] ----------------
__global__ __launch_bounds__(256) void w1r_kernel(
    const float* __restrict__ w1, float* __restrict__ w1r) {
  int idx = blockIdx.x * 256 + threadIdx.x;
  int ic = idx / 1152, rem = idx - ic * 1152;
  int tap = rem >> 7, oc = rem & 127;
  w1r[idx] = w1[(size_t)oc * 2304 + ic * 9 + tap];
}

// ---------------- K2.5: G GEMM ----------------
__global__ __launch_bounds__(256) void gtab_gemm_kernel(
    const float* __restrict__ feat, const float* __restrict__ w1r,
    float* __restrict__ G) {
  __shared__ float As[16 * 132];
  __shared__ float4 Bs4[2048];
  int tid = threadIdx.x;
  int r0 = blockIdx.x * 16;
  int n0 = blockIdx.y * 64;
  int r = tid >> 4;
  int c4 = (tid & 15) << 2;
  float4 acc = make_float4(0.f, 0.f, 0.f, 0.f);
  for (int k0 = 0; k0 < 256; k0 += 128) {
    __syncthreads();
    #pragma unroll
    for (int i = 0; i < 8; ++i) {
      int idx = tid + i * 256;
      As[(idx >> 7) * 132 + (idx & 127)] =
          feat[(size_t)(r0 + (idx >> 7)) * 256 + k0 + (idx & 127)];
    }
    #pragma unroll
    for (int i = 0; i < 8; ++i) {
      int idx = tid + i * 256;
      Bs4[idx] = *(const float4*)(w1r + (size_t)(k0 + (idx >> 4)) * 1152 + n0 + ((idx & 15) << 2));
    }
    __syncthreads();
    const float* ar = As + r * 132;
    #pragma unroll 8
    for (int k = 0; k < 128; ++k) {
      float a = ar[k];
      float4 bv = Bs4[(k << 4) + (c4 >> 2)];
      acc.x = fmaf(a, bv.x, acc.x); acc.y = fmaf(a, bv.y, acc.y);
      acc.z = fmaf(a, bv.z, acc.z); acc.w = fmaf(a, bv.w, acc.w);
    }
  }
  int row = r0 + r;
  if ((row & 511) == 0) acc = make_float4(0.f, 0.f, 0.f, 0.f);
  *(float4*)(G + (size_t)row * 1152 + n0 + c4) = acc;
}

// ---------------- K2.6: Gall ----------------
__global__ __launch_bounds__(256) void gall_kernel(
    const float* __restrict__ G, float* __restrict__ Gall) {
  int idx = blockIdx.x * 256 + threadIdx.x;
  int row = idx >> 7, oc = idx & 127;
  const float* gr = G + (size_t)row * 1152 + oc;
  float s = 0.f;
  #pragma unroll
  for (int t = 0; t < 9; ++t) s += gr[t * 128];
  Gall[idx] = s;
}

// ---------------- K2.7: w2T bf16 ----------------
__global__ __launch_bounds__(256) void w2t_kernel(
    const float* __restrict__ w2, ushort* __restrict__ w2t) {
  int oc = blockIdx.x;
  for (int k = threadIdx.x; k < 1152; k += 256) {
    int tap = k >> 7, ic = k & 127;
    w2t[(size_t)oc * 1152 + k] = f2bf(w2[(size_t)oc * 1152 + ic * 9 + tap]);
  }
}

// ---------------- K3: conv1 gather + BN1 + ReLU -> buf1 (bf16 NHWC) ----------------
// buf1: [(SR+2) rows][512 w][128 ic] bf16 ; row i <-> global h = hstart + i
__global__ __launch_bounds__(256) void conv1_gather_kernel(
    const int* __restrict__ winner,
    const float* __restrict__ G, const float* __restrict__ Gall,
    const float* __restrict__ cb, const float* __restrict__ g,
    const float* __restrict__ bt, const float* __restrict__ m,
    const float* __restrict__ v,
    ushort* __restrict__ buf1, size_t bstride, int b0, int hstart) {
  __shared__ float sscl[128], sshf[128];
  int tid = threadIdx.x;
  if (tid < 128) {
    float s = g[tid] * rsqrtf(v[tid] + 1e-5f);
    sscl[tid] = s;
    sshf[tid] = (cb[tid] - m[tid]) * s + bt[tid];
  }
  __syncthreads();
  int b = b0 + blockIdx.z;
  int px = blockIdx.x * 256 + tid;
  int r = px >> 9, w = px & 511;
  int h = hstart + r;
  ushort* dst = buf1 + (size_t)blockIdx.z * bstride + (size_t)px * 128;
  if (h < 0 || h >= HH) {
    uint4 z = make_uint4(0, 0, 0, 0);
    #pragma unroll
    for (int j = 0; j < 16; ++j) *(uint4*)(dst + j * 8) = z;
    return;
  }
  const int* wb = winner + (b << 18);
  int win[9];
  #pragma unroll
  for (int ky = 0; ky < 3; ++ky)
    #pragma unroll
    for (int kx = 0; kx < 3; ++kx) {
      int hp = h - 1 + ky, wp = w - 1 + kx;
      int s = 0;
      if (hp >= 0 && hp < HH && wp >= 0 && wp < WW) s = wb[(hp << 9) + wp];
      win[ky * 3 + kx] = s;
    }
  bool alleq = true;
  #pragma unroll
  for (int t = 1; t < 9; ++t) alleq = alleq && (win[t] == win[0]);

  if (alleq) {
    const float4* gp = (const float4*)(Gall + ((((size_t)b << 9) + win[0]) << 7));
    #pragma unroll
    for (int o8 = 0; o8 < 16; ++o8) {
      float4 a0 = gp[o8 * 2], a1 = gp[o8 * 2 + 1];
      const float* sc = &sscl[o8 * 8];
      const float* sh = &sshf[o8 * 8];
      union { ushort us[8]; uint4 v4; } pk;
      pk.us[0] = f2bf(fmaxf(fmaf(a0.x, sc[0], sh[0]), 0.f));
      pk.us[1] = f2bf(fmaxf(fmaf(a0.y, sc[1], sh[1]), 0.f));
      pk.us[2] = f2bf(fmaxf(fmaf(a0.z, sc[2], sh[2]), 0.f));
      pk.us[3] = f2bf(fmaxf(fmaf(a0.w, sc[3], sh[3]), 0.f));
      pk.us[4] = f2bf(fmaxf(fmaf(a1.x, sc[4], sh[4]), 0.f));
      pk.us[5] = f2bf(fmaxf(fmaf(a1.y, sc[5], sh[5]), 0.f));
      pk.us[6] = f2bf(fmaxf(fmaf(a1.z, sc[6], sh[6]), 0.f));
      pk.us[7] = f2bf(fmaxf(fmaf(a1.w, sc[7], sh[7]), 0.f));
      *(uint4*)(dst + o8 * 8) = pk.v4;
    }
  } else {
    size_t off[9];
    #pragma unroll
    for (int t = 0; t < 9; ++t)
      off[t] = ((size_t)((b << 9) + win[t])) * 1152 + t * 128;
    #pragma unroll
    for (int o8 = 0; o8 < 16; ++o8) {
      float4 a0 = make_float4(0, 0, 0, 0), a1 = a0;
      #pragma unroll
      for (int t = 0; t < 9; ++t) {
        const float4* gp = (const float4*)(G + off[t] + o8 * 8);
        float4 g0 = gp[0], g1 = gp[1];
        a0.x += g0.x; a0.y += g0.y; a0.z += g0.z; a0.w += g0.w;
        a1.x += g1.x; a1.y += g1.y; a1.z += g1.z; a1.w += g1.w;
      }
      const float* sc = &sscl[o8 * 8];
      const float* sh = &sshf[o8 * 8];
      union { ushort us[8]; uint4 v4; } pk;
      pk.us[0] = f2bf(fmaxf(fmaf(a0.x, sc[0], sh[0]), 0.f));
      pk.us[1] = f2bf(fmaxf(fmaf(a0.y, sc[1], sh[1]), 0.f));
      pk.us[2] = f2bf(fmaxf(fmaf(a0.z, sc[2], sh[2]), 0.f));
      pk.us[3] = f2bf(fmaxf(fmaf(a0.w, sc[3], sh[3]), 0.f));
      pk.us[4] = f2bf(fmaxf(fmaf(a1.x, sc[4], sh[4]), 0.f));
      pk.us[5] = f2bf(fmaxf(fmaf(a1.y, sc[5], sh[5]), 0.f));
      pk.us[6] = f2bf(fmaxf(fmaf(a1.z, sc[6], sh[6]), 0.f));
      pk.us[7] = f2bf(fmaxf(fmaf(a1.w, sc[7], sh[7]), 0.f));
      *(uint4*)(dst + o8 * 8) = pk.v4;
    }
  }
}

// ---------------- K4: conv2 MFMA (implicit GEMM) + BN2 + ReLU + fused conv3 ----------------
// Block = 8 output rows x 64 w x 64 oc; 4 waves; wave wv = rows {2wv,2wv+1} (128 px)
// x ALL 64 oc as an 8x4 fragment tile: per tap 8 A + 4 B reads for 32 MFMA
// (2.67 MFMA/ds_read -> 42.7 FLOP/LDS-byte, vs 32 in the 4x4 tile).
// A tile 10 rows x 66 cols x 32ic in LDS (42.2KB) + B 36.9KB -> 81.5KB, 2 blocks/CU.
__global__ __launch_bounds__(256) void conv2_mfma_kernel(
    const ushort* __restrict__ buf1, const ushort* __restrict__ w2t,
    const float* __restrict__ cb, const float* __restrict__ g,
    const float* __restrict__ bt, const float* __restrict__ m_,
    const float* __restrict__ v_,
    const float* __restrict__ w3, const float* __restrict__ b3,
    float* __restrict__ out, size_t bstride, int b0, int hs0, int SR) {
  __shared__ uint4 lds4[5092];              // 81472 B
  char* smem = (char*)lds4;
  int tid = threadIdx.x;
  int w0 = blockIdx.x * 64;
  int oh0 = blockIdx.y * 8;                 // 8 output rows per block
  int b = b0 + blockIdx.z;
  const ushort* B1 = buf1 + (size_t)blockIdx.z * bstride;
  int wv = tid >> 6, lane = tid & 63;
  int l15 = lane & 15, l4 = lane >> 4;

  float scl[4], shf[4];
  #pragma unroll
  for (int nf = 0; nf < 4; ++nf) {
    int oc = nf * 16 + l15;
    float s = g[oc] * rsqrtf(v_[oc] + 1e-5f);
    scl[nf] = s;
    shf[nf] = (cb[oc] - m_[oc]) * s + bt[oc];
  }

  // A fragment addresses: mf = (row-of-2)*4 + colgroup; A-tile row = 2wv + (mf>>2) (+ky)
  int aaddr[8][3];
  #pragma unroll
  for (int mf = 0; mf < 8; ++mf)
    #pragma unroll
    for (int kx = 0; kx < 3; ++kx) {
      int baserow = 2 * wv + (mf >> 2);
      int col = (mf & 3) * 16 + l15 + kx;
      aaddr[mf][kx] = baserow * 4224 + (col << 6) + ((l4 << 4) ^ (((col >> 1) & 3) << 4));
    }
  int baddr[4];
  #pragma unroll
  for (int nf = 0; nf < 4; ++nf) {
    int n = nf * 16 + l15;
    baddr[nf] = LDSB + (n << 6) + ((l4 << 4) ^ (((n >> 1) & 3) << 4));
  }

  f32x4 acc[8][4];
  #pragma unroll
  for (int mf = 0; mf < 8; ++mf)
    #pragma unroll
    for (int nf = 0; nf < 4; ++nf)
      acc[mf][nf] = (f32x4){0.f, 0.f, 0.f, 0.f};

  int bn = tid >> 2, bslot = tid & 3;
  int bd = LDSB + (bn << 6) + ((bslot << 4) ^ (((bn >> 1) & 3) << 4));

  for (int chunk = 0; chunk < 4; ++chunk) {
    int ic0 = chunk * 32;
    __syncthreads();
    // ---- A stage: 10 rows x 66 cols x 4 slots = 2640 x 16B, in two batches ----
#define ADEC(II, AV, AD) { \
      int i_ = (II); int slot = i_ & 3; int q = i_ >> 2; \
      int r_ = (q * 993) >> 16; int c_ = q - r_ * 66; \
      int wg = w0 - 1 + c_; \
      AD = ((r_ * 66 + c_) << 6) + ((slot << 4) ^ (((c_ >> 1) & 3) << 4)); \
      AV = make_uint4(0, 0, 0, 0); \
      if (wg >= 0 && wg < 512) \
        AV = *(const uint4*)(B1 + ((((size_t)(oh0 + r_)) << 9) + wg) * 128 + ic0 + slot * 8); \
    }
    {
      uint4 av0, av1, av2, av3, av4, av5;
      int ad0, ad1, ad2, ad3, ad4, ad5;
      ADEC(tid, av0, ad0);
      ADEC(tid + 256, av1, ad1);
      ADEC(tid + 512, av2, ad2);
      ADEC(tid + 768, av3, ad3);
      ADEC(tid + 1024, av4, ad4);
      ADEC(tid + 1280, av5, ad5);
      *(uint4*)(smem + ad0) = av0;
      *(uint4*)(smem + ad1) = av1;
      *(uint4*)(smem + ad2) = av2;
      *(uint4*)(smem + ad3) = av3;
      *(uint4*)(smem + ad4) = av4;
      *(uint4*)(smem + ad5) = av5;
    }
    {
      uint4 av6, av7, av8, av9, av10;
      int ad6, ad7, ad8, ad9, ad10 = 0;
      av10 = make_uint4(0, 0, 0, 0);
      ADEC(tid + 1536, av6, ad6);
      ADEC(tid + 1792, av7, ad7);
      ADEC(tid + 2048, av8, ad8);
      ADEC(tid + 2304, av9, ad9);
      if (tid < 80) ADEC(tid + 2560, av10, ad10);
      *(uint4*)(smem + ad6) = av6;
      *(uint4*)(smem + ad7) = av7;
      *(uint4*)(smem + ad8) = av8;
      *(uint4*)(smem + ad9) = av9;
      if (tid < 80) *(uint4*)(smem + ad10) = av10;
    }
#undef ADEC
    {
      uint4 bv[9];
      const ushort* wsrc = w2t + (size_t)bn * 1152 + ic0 + bslot * 8;
      #pragma unroll
      for (int j = 0; j < 9; ++j) bv[j] = *(const uint4*)(wsrc + j * 128);
      #pragma unroll
      for (int j = 0; j < 9; ++j) *(uint4*)(smem + bd + j * 4096) = bv[j];
    }
    __syncthreads();

    #pragma unroll
    for (int ky = 0; ky < 3; ++ky) {
      #pragma unroll
      for (int kx = 0; kx < 3; ++kx) {
        const int tap = ky * 3 + kx;
        bf16x8 bf0 = *(const bf16x8*)(smem + baddr[0] + tap * 4096);
        bf16x8 bf1 = *(const bf16x8*)(smem + baddr[1] + tap * 4096);
        bf16x8 bf2 = *(const bf16x8*)(smem + baddr[2] + tap * 4096);
        bf16x8 bf3 = *(const bf16x8*)(smem + baddr[3] + tap * 4096);
        #pragma unroll
        for (int mf = 0; mf < 8; ++mf) {
          bf16x8 af = *(const bf16x8*)(smem + aaddr[mf][kx] + ky * 4224);
          acc[mf][0] = __builtin_amdgcn_mfma_f32_16x16x32_bf16(af, bf0, acc[mf][0], 0, 0, 0);
          acc[mf][1] = __builtin_amdgcn_mfma_f32_16x16x32_bf16(af, bf1, acc[mf][1], 0, 0, 0);
          acc[mf][2] = __builtin_amdgcn_mfma_f32_16x16x32_bf16(af, bf2, acc[mf][2], 0, 0, 0);
          acc[mf][3] = __builtin_amdgcn_mfma_f32_16x16x32_bf16(af, bf3, acc[mf][3], 0, 0, 0);
        }
      }
    }
  }

  // ---- epilogue: four 128-px quarter-passes (wave q -> scratch [128][66] -> conv3) ----
  __syncthreads();
  #pragma unroll
  for (int q = 0; q < 4; ++q) {
    if (q) __syncthreads();
    if (wv == q) {
      #pragma unroll
      for (int mf = 0; mf < 8; ++mf)
        #pragma unroll
        for (int nf = 0; nf < 4; ++nf)
          #pragma unroll
          for (int rr = 0; rr < 4; ++rr) {
            int px = (mf >> 2) * 64 + (mf & 3) * 16 + l4 * 4 + rr;   // 0..127
            int oc = nf * 16 + l15;
            float val = fmaxf(fmaf(acc[mf][nf][rr], scl[nf], shf[nf]), 0.f);
            *(float*)(smem + (px * 66 + oc) * 4) = val;
          }
    }
    if (q == 0 && tid >= 128) {
      int idx = tid - 128;
      #pragma unroll
      for (int j = 0; j < 2; ++j) {
        int ii = idx + j * 128;
        if (ii < 144) *(uint4*)(smem + W3_OFF + ii * 16) = *(const uint4*)(w3 + ii * 4);
      }
      if (idx < NC) *(float*)(smem + B3_OFF + idx * 4) = b3[idx];
    }
    __syncthreads();
    if (tid < 128) {
      const float* w3f = (const float*)(smem + W3_OFF);
      const float* b3f = (const float*)(smem + B3_OFF);
      float a9[NC];
      #pragma unroll
      for (int c = 0; c < NC; ++c) a9[c] = b3f[c];
      #pragma unroll 8
      for (int j = 0; j < 32; ++j) {
        float2 xv = *(const float2*)(smem + (tid * 66 + 2 * j) * 4);
        #pragma unroll
        for (int c = 0; c < NC; ++c)
          a9[c] = fmaf(xv.x, w3f[c * 64 + 2 * j], fmaf(xv.y, w3f[c * 64 + 2 * j + 1], a9[c]));
      }
      int h = hs0 + oh0 + q * 2 + (tid >> 6);
      int w = w0 + (tid & 63);
      size_t base = ((size_t)b * NC) * 262144 + (size_t)h * 512 + w;
      #pragma unroll
      for (int c = 0; c < NC; ++c) out[base + (size_t)c * 262144] = a9[c];
    }
  }
}

extern "C" void kernel_launch(void* const* d_in, const int* in_sizes, int n_in,
                              void* d_out, int out_size, void* d_ws, size_t ws_size,
                              hipStream_t stream) {
  const float* hs  = (const float*)d_in[0];
  const int* bbox  = (const int*)d_in[1];
  const int* amask = (const int*)d_in[2];
  const float* pw  = (const float*)d_in[3];
  const float* pb  = (const float*)d_in[4];
  const float* w1  = (const float*)d_in[5];
  const float* c1b = (const float*)d_in[6];
  const float* g1  = (const float*)d_in[7];
  const float* b1  = (const float*)d_in[8];
  const float* m1  = (const float*)d_in[9];
  const float* v1  = (const float*)d_in[10];
  const float* w2  = (const float*)d_in[11];
  const float* c2b = (const float*)d_in[12];
  const float* g2  = (const float*)d_in[13];
  const float* b2  = (const float*)d_in[14];
  const float* m2  = (const float*)d_in[15];
  const float* v2  = (const float*)d_in[16];
  const float* w3  = (const float*)d_in[17];
  const float* b3  = (const float*)d_in[18];
  float* out = (float*)d_out;

  char* wsb = (char*)d_ws;
  float*  feat   = (float*)(wsb + 0);             // 1 MB
  int*    winner = (int*)(wsb + 1048576);         // 2 MB
  float*  G      = (float*)(wsb + 3145728);       // 4.5 MB
  float*  Gall   = (float*)(wsb + 7864320);       // 0.5 MB
  float*  w1r    = (float*)(wsb + 8388608);       // 1.18 MB
  ushort* w2t    = (ushort*)(wsb + 10485760);     // 144 KB
  ushort* buf1   = (ushort*)(wsb + 10747904);

  int SR = 512;
  while (SR > 32) {
    if (10747904 + (size_t)(SR + 2) * 131072 <= ws_size) break;
    SR >>= 1;
  }
  size_t b1s = (size_t)(SR + 2) * 65536;   // elems per batch
  int NB = (SR == 512 && ws_size >= 10747904 + 4 * b1s) ? 2 : 1;

  hipMemsetAsync(winner, 0, 2097152, stream);
  proj_gemm_kernel<<<dim3(64, 4), 256, 0, stream>>>(hs, pw, pb, feat);
  scatter_kernel<<<1024, 64, 0, stream>>>(bbox, amask, winner);
  w1r_kernel<<<1152, 256, 0, stream>>>(w1, w1r);
  gtab_gemm_kernel<<<dim3(64, 18), 256, 0, stream>>>(feat, w1r, G);
  gall_kernel<<<512, 256, 0, stream>>>(G, Gall);
  w2t_kernel<<<64, 256, 0, stream>>>(w2, w2t);

  if (NB == 2) {
    conv1_gather_kernel<<<dim3((SR + 2) * 512 / 256, 1, 2), 256, 0, stream>>>(
        winner, G, Gall, c1b, g1, b1, m1, v1, buf1, b1s, 0, -1);
    conv2_mfma_kernel<<<dim3(8, SR / 8, 2), 256, 0, stream>>>(
        buf1, w2t, c2b, g2, b2, m2, v2, w3, b3, out, b1s, 0, 0, SR);
  } else {
    int nstripes = 512 / SR;
    for (int b = 0; b < 2; ++b) {
      for (int s = 0; s < nstripes; ++s) {
        int hs0 = s * SR;
        conv1_gather_kernel<<<dim3((SR + 2) * 512 / 256, 1, 1), 256, 0, stream>>>(
            winner, G, Gall, c1b, g1, b1, m1, v1, buf1, (size_t)0, b, hs0 - 1);
        conv2_mfma_kernel<<<dim3(8, SR / 8, 1), 256, 0, stream>>>(
            buf1, w2t, c2b, g2, b2, m2, v2, w3, b3, out, (size_t)0, b, hs0, SR);
      }
    }
  }
}

// Round 14
// 310.205 us; speedup vs baseline: 1.1776x; 1.1776x over previous
//
#include <hip/hip_runtime.h>
#include <hip/hip_bf16.h>

typedef __bf16 bf16x8 __attribute__((ext_vector_type(8)));
typedef float f32x4 __attribute__((ext_vector_type(4)));
typedef const __attribute__((address_space(1))) unsigned int* gp_t;
typedef __attribute__((address_space(3))) unsigned int* lp_t;

#define HH 512
#define WW 512
#define NC 9
#define LDSB 25600        // A region: 400 cells x 64B (396 real + 4 dummy)
#define W3_OFF 62464      // LDSB + 9*4096
#define B3_OFF 64768

static __device__ __forceinline__ ushort f2bf(float x) {
  union { float f; unsigned u; } c; c.f = x;
  unsigned r = c.u + 0x7FFFu + ((c.u >> 16) & 1u);
  return (ushort)(r >> 16);
}

// ---------------- K1: proj GEMM: feat[1024,256] = hs[1024,768] @ pw[768,256] + pb ----------------
__global__ __launch_bounds__(256) void proj_gemm_kernel(
    const float* __restrict__ hs, const float* __restrict__ pw,
    const float* __restrict__ pb, float* __restrict__ feat) {
  __shared__ float As[16 * 132];
  __shared__ float4 Bs4[2048];
  int tid = threadIdx.x;
  int r0 = blockIdx.x * 16;
  int n0 = blockIdx.y * 64;
  int r = tid >> 4;
  int c4 = (tid & 15) << 2;
  float4 acc = *(const float4*)(pb + n0 + c4);
  for (int k0 = 0; k0 < 768; k0 += 128) {
    __syncthreads();
    #pragma unroll
    for (int i = 0; i < 8; ++i) {
      int idx = tid + i * 256;
      As[(idx >> 7) * 132 + (idx & 127)] =
          hs[(size_t)(r0 + (idx >> 7)) * 768 + k0 + (idx & 127)];
    }
    #pragma unroll
    for (int i = 0; i < 8; ++i) {
      int idx = tid + i * 256;
      Bs4[idx] = *(const float4*)(pw + (size_t)(k0 + (idx >> 4)) * 256 + n0 + ((idx & 15) << 2));
    }
    __syncthreads();
    const float* ar = As + r * 132;
    #pragma unroll 8
    for (int k = 0; k < 128; ++k) {
      float a = ar[k];
      float4 bv = Bs4[(k << 4) + (c4 >> 2)];
      acc.x = fmaf(a, bv.x, acc.x); acc.y = fmaf(a, bv.y, acc.y);
      acc.z = fmaf(a, bv.z, acc.z); acc.w = fmaf(a, bv.w, acc.w);
    }
  }
  *(float4*)(feat + (size_t)(r0 + r) * 256 + n0 + c4) = acc;
}

// ---------------- K2: winner map via atomic scatter ----------------
__global__ __launch_bounds__(64) void scatter_kernel(
    const int* __restrict__ bbox, const int* __restrict__ amask,
    int* __restrict__ winner) {
  int token = blockIdx.x;
  int b = token >> 9, s = token & 511;
  if (s == 0) return;
  const int* bb = bbox + (size_t)token * 4;
  int x1 = (bb[0] * 512) / 1000; if (x1 < 0) x1 = 0;
  int y1 = (bb[1] * 512) / 1000; if (y1 < 0) y1 = 0;
  int x2 = (bb[2] * 512) / 1000; if (x2 > 511) x2 = 511;
  int y2 = (bb[3] * 512) / 1000; if (y2 > 511) y2 = 511;
  if (amask[token] != 1 || x2 <= x1 || y2 <= y1) return;
  int lane = threadIdx.x;
  for (int yy = y1; yy < y2; ++yy) {
    int rowbase = (b << 18) + (yy << 9);
    for (int xx = x1 + lane; xx < x2; xx += 64)
      atomicMax(&winner[rowbase + xx], s);
  }
}

// ---------------- K2.4: w1r[ic][tap*128+oc] ----------------
__global__ __launch_bounds__(256) void w1r_kernel(
    const float* __restrict__ w1, float* __restrict__ w1r) {
  int idx = blockIdx.x * 256 + threadIdx.x;
  int ic = idx / 1152, rem = idx - ic * 1152;
  int tap = rem >> 7, oc = rem & 127;
  w1r[idx] = w1[(size_t)oc * 2304 + ic * 9 + tap];
}

// ---------------- K2.5: G GEMM ----------------
__global__ __launch_bounds__(256) void gtab_gemm_kernel(
    const float* __restrict__ feat, const float* __restrict__ w1r,
    float* __restrict__ G) {
  __shared__ float As[16 * 132];
  __shared__ float4 Bs4[2048];
  int tid = threadIdx.x;
  int r0 = blockIdx.x * 16;
  int n0 = blockIdx.y * 64;
  int r = tid >> 4;
  int c4 = (tid & 15) << 2;
  float4 acc = make_float4(0.f, 0.f, 0.f, 0.f);
  for (int k0 = 0; k0 < 256; k0 += 128) {
    __syncthreads();
    #pragma unroll
    for (int i = 0; i < 8; ++i) {
      int idx = tid + i * 256;
      As[(idx >> 7) * 132 + (idx & 127)] =
          feat[(size_t)(r0 + (idx >> 7)) * 256 + k0 + (idx & 127)];
    }
    #pragma unroll
    for (int i = 0; i < 8; ++i) {
      int idx = tid + i * 256;
      Bs4[idx] = *(const float4*)(w1r + (size_t)(k0 + (idx >> 4)) * 1152 + n0 + ((idx & 15) << 2));
    }
    __syncthreads();
    const float* ar = As + r * 132;
    #pragma unroll 8
    for (int k = 0; k < 128; ++k) {
      float a = ar[k];
      float4 bv = Bs4[(k << 4) + (c4 >> 2)];
      acc.x = fmaf(a, bv.x, acc.x); acc.y = fmaf(a, bv.y, acc.y);
      acc.z = fmaf(a, bv.z, acc.z); acc.w = fmaf(a, bv.w, acc.w);
    }
  }
  int row = r0 + r;
  if ((row & 511) == 0) acc = make_float4(0.f, 0.f, 0.f, 0.f);
  *(float4*)(G + (size_t)row * 1152 + n0 + c4) = acc;
}

// ---------------- K2.6: Gall ----------------
__global__ __launch_bounds__(256) void gall_kernel(
    const float* __restrict__ G, float* __restrict__ Gall) {
  int idx = blockIdx.x * 256 + threadIdx.x;
  int row = idx >> 7, oc = idx & 127;
  const float* gr = G + (size_t)row * 1152 + oc;
  float s = 0.f;
  #pragma unroll
  for (int t = 0; t < 9; ++t) s += gr[t * 128];
  Gall[idx] = s;
}

// ---------------- K2.7: w2T bf16 ----------------
__global__ __launch_bounds__(256) void w2t_kernel(
    const float* __restrict__ w2, ushort* __restrict__ w2t) {
  int oc = blockIdx.x;
  for (int k = threadIdx.x; k < 1152; k += 256) {
    int tap = k >> 7, ic = k & 127;
    w2t[(size_t)oc * 1152 + k] = f2bf(w2[(size_t)oc * 1152 + ic * 9 + tap]);
  }
}

// ---------------- K3: conv1 gather + BN1 + ReLU -> buf1 (bf16 NHWC) ----------------
// buf1: [(SR+2) rows][512 w][128 ic] bf16 ; row i <-> global h = hstart + i
__global__ __launch_bounds__(256) void conv1_gather_kernel(
    const int* __restrict__ winner,
    const float* __restrict__ G, const float* __restrict__ Gall,
    const float* __restrict__ cb, const float* __restrict__ g,
    const float* __restrict__ bt, const float* __restrict__ m,
    const float* __restrict__ v,
    ushort* __restrict__ buf1, size_t bstride, int b0, int hstart) {
  __shared__ float sscl[128], sshf[128];
  int tid = threadIdx.x;
  if (tid < 128) {
    float s = g[tid] * rsqrtf(v[tid] + 1e-5f);
    sscl[tid] = s;
    sshf[tid] = (cb[tid] - m[tid]) * s + bt[tid];
  }
  __syncthreads();
  int b = b0 + blockIdx.z;
  int px = blockIdx.x * 256 + tid;
  int r = px >> 9, w = px & 511;
  int h = hstart + r;
  ushort* dst = buf1 + (size_t)blockIdx.z * bstride + (size_t)px * 128;
  if (h < 0 || h >= HH) {
    uint4 z = make_uint4(0, 0, 0, 0);
    #pragma unroll
    for (int j = 0; j < 16; ++j) *(uint4*)(dst + j * 8) = z;
    return;
  }
  const int* wb = winner + (b << 18);
  int win[9];
  #pragma unroll
  for (int ky = 0; ky < 3; ++ky)
    #pragma unroll
    for (int kx = 0; kx < 3; ++kx) {
      int hp = h - 1 + ky, wp = w - 1 + kx;
      int s = 0;
      if (hp >= 0 && hp < HH && wp >= 0 && wp < WW) s = wb[(hp << 9) + wp];
      win[ky * 3 + kx] = s;
    }
  bool alleq = true;
  #pragma unroll
  for (int t = 1; t < 9; ++t) alleq = alleq && (win[t] == win[0]);

  if (alleq) {
    const float4* gp = (const float4*)(Gall + ((((size_t)b << 9) + win[0]) << 7));
    #pragma unroll
    for (int o8 = 0; o8 < 16; ++o8) {
      float4 a0 = gp[o8 * 2], a1 = gp[o8 * 2 + 1];
      const float* sc = &sscl[o8 * 8];
      const float* sh = &sshf[o8 * 8];
      union { ushort us[8]; uint4 v4; } pk;
      pk.us[0] = f2bf(fmaxf(fmaf(a0.x, sc[0], sh[0]), 0.f));
      pk.us[1] = f2bf(fmaxf(fmaf(a0.y, sc[1], sh[1]), 0.f));
      pk.us[2] = f2bf(fmaxf(fmaf(a0.z, sc[2], sh[2]), 0.f));
      pk.us[3] = f2bf(fmaxf(fmaf(a0.w, sc[3], sh[3]), 0.f));
      pk.us[4] = f2bf(fmaxf(fmaf(a1.x, sc[4], sh[4]), 0.f));
      pk.us[5] = f2bf(fmaxf(fmaf(a1.y, sc[5], sh[5]), 0.f));
      pk.us[6] = f2bf(fmaxf(fmaf(a1.z, sc[6], sh[6]), 0.f));
      pk.us[7] = f2bf(fmaxf(fmaf(a1.w, sc[7], sh[7]), 0.f));
      *(uint4*)(dst + o8 * 8) = pk.v4;
    }
  } else {
    size_t off[9];
    #pragma unroll
    for (int t = 0; t < 9; ++t)
      off[t] = ((size_t)((b << 9) + win[t])) * 1152 + t * 128;
    #pragma unroll
    for (int o8 = 0; o8 < 16; ++o8) {
      float4 a0 = make_float4(0, 0, 0, 0), a1 = a0;
      #pragma unroll
      for (int t = 0; t < 9; ++t) {
        const float4* gp = (const float4*)(G + off[t] + o8 * 8);
        float4 g0 = gp[0], g1 = gp[1];
        a0.x += g0.x; a0.y += g0.y; a0.z += g0.z; a0.w += g0.w;
        a1.x += g1.x; a1.y += g1.y; a1.z += g1.z; a1.w += g1.w;
      }
      const float* sc = &sscl[o8 * 8];
      const float* sh = &sshf[o8 * 8];
      union { ushort us[8]; uint4 v4; } pk;
      pk.us[0] = f2bf(fmaxf(fmaf(a0.x, sc[0], sh[0]), 0.f));
      pk.us[1] = f2bf(fmaxf(fmaf(a0.y, sc[1], sh[1]), 0.f));
      pk.us[2] = f2bf(fmaxf(fmaf(a0.z, sc[2], sh[2]), 0.f));
      pk.us[3] = f2bf(fmaxf(fmaf(a0.w, sc[3], sh[3]), 0.f));
      pk.us[4] = f2bf(fmaxf(fmaf(a1.x, sc[4], sh[4]), 0.f));
      pk.us[5] = f2bf(fmaxf(fmaf(a1.y, sc[5], sh[5]), 0.f));
      pk.us[6] = f2bf(fmaxf(fmaf(a1.z, sc[6], sh[6]), 0.f));
      pk.us[7] = f2bf(fmaxf(fmaf(a1.w, sc[7], sh[7]), 0.f));
      *(uint4*)(dst + o8 * 8) = pk.v4;
    }
  }
}

// ---------------- K4: conv2 MFMA (implicit GEMM) + BN2 + ReLU + fused conv3 ----------------
// r12 structure (M=256 px x N=64 oc, 4 waves, wave = 4x4 fragment tile) with
// staging via global_load_lds width=16: LDS dests are LINEAR in item index;
// the r12 slot-XOR layout is reproduced by pre-swizzling the GLOBAL source slot
// (involution; fragment readers unchanged). OOB halo lanes read G row 0 (zeros).
__global__ __launch_bounds__(256) void conv2_mfma_kernel(
    const ushort* __restrict__ buf1, const ushort* __restrict__ w2t,
    const float* __restrict__ zsrc,
    const float* __restrict__ cb, const float* __restrict__ g,
    const float* __restrict__ bt, const float* __restrict__ m_,
    const float* __restrict__ v_,
    const float* __restrict__ w3, const float* __restrict__ b3,
    float* __restrict__ out, size_t bstride, int b0, int hs0, int SR) {
  __shared__ uint4 lds4[4051];              // 64816 B
  char* smem = (char*)lds4;
  int tid = threadIdx.x;
  int w0 = blockIdx.x * 64;
  int oh0 = blockIdx.y * 4;                 // 4 output rows per block
  int b = b0 + blockIdx.z;
  const ushort* B1 = buf1 + (size_t)blockIdx.z * bstride;
  int wv = tid >> 6, lane = tid & 63;
  int l15 = lane & 15, l4 = lane >> 4;
  int wvbase = wv * 1024;

  float scl[4], shf[4];
  #pragma unroll
  for (int nf = 0; nf < 4; ++nf) {
    int oc = nf * 16 + l15;
    float s = g[oc] * rsqrtf(v_[oc] + 1e-5f);
    scl[nf] = s;
    shf[nf] = (cb[oc] - m_[oc]) * s + bt[oc];
  }

  // A fragment addresses: wave's output row = wv; A-row = wv + ky
  int aaddr[4][3];
  #pragma unroll
  for (int mf = 0; mf < 4; ++mf)
    #pragma unroll
    for (int kx = 0; kx < 3; ++kx) {
      int col = mf * 16 + l15 + kx;
      aaddr[mf][kx] = wv * 4224 + (col << 6) + ((l4 << 4) ^ (((col >> 1) & 3) << 4));
    }
  int baddr[4];
  #pragma unroll
  for (int nf = 0; nf < 4; ++nf) {
    int n = nf * 16 + l15;
    baddr[nf] = LDSB + (n << 6) + ((l4 << 4) ^ (((n >> 1) & 3) << 4));
  }

  f32x4 acc[4][4];
  #pragma unroll
  for (int mf = 0; mf < 4; ++mf)
    #pragma unroll
    for (int nf = 0; nf < 4; ++nf)
      acc[mf][nf] = (f32x4){0.f, 0.f, 0.f, 0.f};

  for (int chunk = 0; chunk < 4; ++chunk) {
    int ic0 = chunk * 32;
    __syncthreads();
    // ---- A stage: 1600 items x 16B via global_load_lds (linear LDS dest) ----
#define GLLA(K) { \
      int i_ = tid + (K) * 256; \
      int slot = i_ & 3; int q = i_ >> 2; \
      int r_ = (q * 993) >> 16; int c_ = q - r_ * 66; \
      int wg = w0 - 1 + c_; \
      int slot2 = slot ^ ((c_ >> 1) & 3); \
      const char* src = (const char*)zsrc; \
      if (r_ < 6 && wg >= 0 && wg < 512) \
        src = (const char*)(B1 + ((((size_t)(oh0 + r_)) << 9) + wg) * 128 + ic0) + slot2 * 16; \
      __builtin_amdgcn_global_load_lds((gp_t)src, (lp_t)(smem + (K) * 4096 + wvbase), 16, 0, 0); \
    }
    GLLA(0) GLLA(1) GLLA(2) GLLA(3) GLLA(4) GLLA(5)
    if (tid < 64) GLLA(6)
#undef GLLA
    // ---- B stage: 9 taps x 256 items x 16B (linear LDS dest per tap) ----
#define GLLB(J) { \
      int bn2 = tid >> 2, bs = tid & 3; \
      int bs2 = bs ^ ((bn2 >> 1) & 3); \
      const char* src = (const char*)w2t + (size_t)bn2 * 2304 + (J) * 256 + ic0 * 2 + bs2 * 16; \
      __builtin_amdgcn_global_load_lds((gp_t)src, (lp_t)(smem + LDSB + (J) * 4096 + wvbase), 16, 0, 0); \
    }
    GLLB(0) GLLB(1) GLLB(2) GLLB(3) GLLB(4) GLLB(5) GLLB(6) GLLB(7) GLLB(8)
#undef GLLB
    __syncthreads();

    #pragma unroll
    for (int ky = 0; ky < 3; ++ky) {
      #pragma unroll
      for (int kx = 0; kx < 3; ++kx) {
        const int tap = ky * 3 + kx;
        bf16x8 bf0 = *(const bf16x8*)(smem + baddr[0] + tap * 4096);
        bf16x8 bf1 = *(const bf16x8*)(smem + baddr[1] + tap * 4096);
        bf16x8 bf2 = *(const bf16x8*)(smem + baddr[2] + tap * 4096);
        bf16x8 bf3 = *(const bf16x8*)(smem + baddr[3] + tap * 4096);
        #pragma unroll
        for (int mf = 0; mf < 4; ++mf) {
          bf16x8 af = *(const bf16x8*)(smem + aaddr[mf][kx] + ky * 4224);
          acc[mf][0] = __builtin_amdgcn_mfma_f32_16x16x32_bf16(af, bf0, acc[mf][0], 0, 0, 0);
          acc[mf][1] = __builtin_amdgcn_mfma_f32_16x16x32_bf16(af, bf1, acc[mf][1], 0, 0, 0);
          acc[mf][2] = __builtin_amdgcn_mfma_f32_16x16x32_bf16(af, bf2, acc[mf][2], 0, 0, 0);
          acc[mf][3] = __builtin_amdgcn_mfma_f32_16x16x32_bf16(af, bf3, acc[mf][3], 0, 0, 0);
        }
      }
    }
  }

  // ---- epilogue: two 128-px halves (rows {0,1} then {2,3}); scratch [128 px][66] f32 ----
  __syncthreads();
  #pragma unroll
  for (int half = 0; half < 2; ++half) {
    if (half) __syncthreads();
    if ((wv >> 1) == half) {
      #pragma unroll
      for (int mf = 0; mf < 4; ++mf)
        #pragma unroll
        for (int nf = 0; nf < 4; ++nf)
          #pragma unroll
          for (int rr = 0; rr < 4; ++rr) {
            int px = (wv & 1) * 64 + mf * 16 + l4 * 4 + rr;   // 0..127
            int oc = nf * 16 + l15;
            float val = fmaxf(fmaf(acc[mf][nf][rr], scl[nf], shf[nf]), 0.f);
            *(float*)(smem + (px * 66 + oc) * 4) = val;
          }
    }
    if (half == 0 && tid >= 128) {
      int idx = tid - 128;
      #pragma unroll
      for (int j = 0; j < 2; ++j) {
        int ii = idx + j * 128;
        if (ii < 144) *(uint4*)(smem + W3_OFF + ii * 16) = *(const uint4*)(w3 + ii * 4);
      }
      if (idx < NC) *(float*)(smem + B3_OFF + idx * 4) = b3[idx];
    }
    __syncthreads();
    if (tid < 128) {
      const float* w3f = (const float*)(smem + W3_OFF);
      const float* b3f = (const float*)(smem + B3_OFF);
      float a9[NC];
      #pragma unroll
      for (int c = 0; c < NC; ++c) a9[c] = b3f[c];
      #pragma unroll 8
      for (int j = 0; j < 32; ++j) {
        float2 xv = *(const float2*)(smem + (tid * 66 + 2 * j) * 4);
        #pragma unroll
        for (int c = 0; c < NC; ++c)
          a9[c] = fmaf(xv.x, w3f[c * 64 + 2 * j], fmaf(xv.y, w3f[c * 64 + 2 * j + 1], a9[c]));
      }
      int h = hs0 + oh0 + half * 2 + (tid >> 6);
      int w = w0 + (tid & 63);
      size_t base = ((size_t)b * NC) * 262144 + (size_t)h * 512 + w;
      #pragma unroll
      for (int c = 0; c < NC; ++c) out[base + (size_t)c * 262144] = a9[c];
    }
  }
}

extern "C" void kernel_launch(void* const* d_in, const int* in_sizes, int n_in,
                              void* d_out, int out_size, void* d_ws, size_t ws_size,
                              hipStream_t stream) {
  const float* hs  = (const float*)d_in[0];
  const int* bbox  = (const int*)d_in[1];
  const int* amask = (const int*)d_in[2];
  const float* pw  = (const float*)d_in[3];
  const float* pb  = (const float*)d_in[4];
  const float* w1  = (const float*)d_in[5];
  const float* c1b = (const float*)d_in[6];
  const float* g1  = (const float*)d_in[7];
  const float* b1  = (const float*)d_in[8];
  const float* m1  = (const float*)d_in[9];
  const float* v1  = (const float*)d_in[10];
  const float* w2  = (const float*)d_in[11];
  const float* c2b = (const float*)d_in[12];
  const float* g2  = (const float*)d_in[13];
  const float* b2  = (const float*)d_in[14];
  const float* m2  = (const float*)d_in[15];
  const float* v2  = (const float*)d_in[16];
  const float* w3  = (const float*)d_in[17];
  const float* b3  = (const float*)d_in[18];
  float* out = (float*)d_out;

  char* wsb = (char*)d_ws;
  float*  feat   = (float*)(wsb + 0);             // 1 MB
  int*    winner = (int*)(wsb + 1048576);         // 2 MB
  float*  G      = (float*)(wsb + 3145728);       // 4.5 MB (row 0 = zeros)
  float*  Gall   = (float*)(wsb + 7864320);       // 0.5 MB
  float*  w1r    = (float*)(wsb + 8388608);       // 1.18 MB
  ushort* w2t    = (ushort*)(wsb + 10485760);     // 144 KB
  ushort* buf1   = (ushort*)(wsb + 10747904);

  int SR = 512;
  while (SR > 32) {
    if (10747904 + (size_t)(SR + 2) * 131072 <= ws_size) break;
    SR >>= 1;
  }
  size_t b1s = (size_t)(SR + 2) * 65536;   // elems per batch
  int NB = (SR == 512 && ws_size >= 10747904 + 4 * b1s) ? 2 : 1;

  hipMemsetAsync(winner, 0, 2097152, stream);
  proj_gemm_kernel<<<dim3(64, 4), 256, 0, stream>>>(hs, pw, pb, feat);
  scatter_kernel<<<1024, 64, 0, stream>>>(bbox, amask, winner);
  w1r_kernel<<<1152, 256, 0, stream>>>(w1, w1r);
  gtab_gemm_kernel<<<dim3(64, 18), 256, 0, stream>>>(feat, w1r, G);
  gall_kernel<<<512, 256, 0, stream>>>(G, Gall);
  w2t_kernel<<<64, 256, 0, stream>>>(w2, w2t);

  if (NB == 2) {
    conv1_gather_kernel<<<dim3((SR + 2) * 512 / 256, 1, 2), 256, 0, stream>>>(
        winner, G, Gall, c1b, g1, b1, m1, v1, buf1, b1s, 0, -1);
    conv2_mfma_kernel<<<dim3(8, SR / 4, 2), 256, 0, stream>>>(
        buf1, w2t, G, c2b, g2, b2, m2, v2, w3, b3, out, b1s, 0, 0, SR);
  } else {
    int nstripes = 512 / SR;
    for (int b = 0; b < 2; ++b) {
      for (int s = 0; s < nstripes; ++s) {
        int hs0 = s * SR;
        conv1_gather_kernel<<<dim3((SR + 2) * 512 / 256, 1, 1), 256, 0, stream>>>(
            winner, G, Gall, c1b, g1, b1, m1, v1, buf1, (size_t)0, b, hs0 - 1);
        conv2_mfma_kernel<<<dim3(8, SR / 4, 1), 256, 0, stream>>>(
            buf1, w2t, G, c2b, g2, b2, m2, v2, w3, b3, out, (size_t)0, b, hs0, SR);
      }
    }
  }
}

// Round 15
// 265.938 us; speedup vs baseline: 1.3736x; 1.1665x over previous
//
#include <hip/hip_runtime.h>
#include <hip/hip_bf16.h>

typedef __bf16 bf16x8 __attribute__((ext_vector_type(8)));
typedef float f32x4 __attribute__((ext_vector_type(4)));

#define HH 512
#define WW 512
#define NC 9
#define LDSB 25344        // A tile: 6 rows x 66 cols x 64B
#define W3_OFF 62208      // after B (25344 + 9*4096)
#define B3_OFF 64512

static __device__ __forceinline__ ushort f2bf(float x) {
  union { float f; unsigned u; } c; c.f = x;
  unsigned r = c.u + 0x7FFFu + ((c.u >> 16) & 1u);
  return (ushort)(r >> 16);
}

// ---------------- K1: proj GEMM: feat[1024,256] = hs[1024,768] @ pw[768,256] + pb ----------------
__global__ __launch_bounds__(256) void proj_gemm_kernel(
    const float* __restrict__ hs, const float* __restrict__ pw,
    const float* __restrict__ pb, float* __restrict__ feat) {
  __shared__ float As[16 * 132];
  __shared__ float4 Bs4[2048];
  int tid = threadIdx.x;
  int r0 = blockIdx.x * 16;
  int n0 = blockIdx.y * 64;
  int r = tid >> 4;
  int c4 = (tid & 15) << 2;
  float4 acc = *(const float4*)(pb + n0 + c4);
  for (int k0 = 0; k0 < 768; k0 += 128) {
    __syncthreads();
    #pragma unroll
    for (int i = 0; i < 8; ++i) {
      int idx = tid + i * 256;
      As[(idx >> 7) * 132 + (idx & 127)] =
          hs[(size_t)(r0 + (idx >> 7)) * 768 + k0 + (idx & 127)];
    }
    #pragma unroll
    for (int i = 0; i < 8; ++i) {
      int idx = tid + i * 256;
      Bs4[idx] = *(const float4*)(pw + (size_t)(k0 + (idx >> 4)) * 256 + n0 + ((idx & 15) << 2));
    }
    __syncthreads();
    const float* ar = As + r * 132;
    #pragma unroll 8
    for (int k = 0; k < 128; ++k) {
      float a = ar[k];
      float4 bv = Bs4[(k << 4) + (c4 >> 2)];
      acc.x = fmaf(a, bv.x, acc.x); acc.y = fmaf(a, bv.y, acc.y);
      acc.z = fmaf(a, bv.z, acc.z); acc.w = fmaf(a, bv.w, acc.w);
    }
  }
  *(float4*)(feat + (size_t)(r0 + r) * 256 + n0 + c4) = acc;
}

// ---------------- K2: winner map via atomic scatter ----------------
__global__ __launch_bounds__(64) void scatter_kernel(
    const int* __restrict__ bbox, const int* __restrict__ amask,
    int* __restrict__ winner) {
  int token = blockIdx.x;
  int b = token >> 9, s = token & 511;
  if (s == 0) return;
  const int* bb = bbox + (size_t)token * 4;
  int x1 = (bb[0] * 512) / 1000; if (x1 < 0) x1 = 0;
  int y1 = (bb[1] * 512) / 1000; if (y1 < 0) y1 = 0;
  int x2 = (bb[2] * 512) / 1000; if (x2 > 511) x2 = 511;
  int y2 = (bb[3] * 512) / 1000; if (y2 > 511) y2 = 511;
  if (amask[token] != 1 || x2 <= x1 || y2 <= y1) return;
  int lane = threadIdx.x;
  for (int yy = y1; yy < y2; ++yy) {
    int rowbase = (b << 18) + (yy << 9);
    for (int xx = x1 + lane; xx < x2; xx += 64)
      atomicMax(&winner[rowbase + xx], s);
  }
}

// ---------------- K2.4: w1r[ic][tap*128+oc] ----------------
__global__ __launch_bounds__(256) void w1r_kernel(
    const float* __restrict__ w1, float* __restrict__ w1r) {
  int idx = blockIdx.x * 256 + threadIdx.x;
  int ic = idx / 1152, rem = idx - ic * 1152;
  int tap = rem >> 7, oc = rem & 127;
  w1r[idx] = w1[(size_t)oc * 2304 + ic * 9 + tap];
}

// ---------------- K2.5: G GEMM ----------------
__global__ __launch_bounds__(256) void gtab_gemm_kernel(
    const float* __restrict__ feat, const float* __restrict__ w1r,
    float* __restrict__ G) {
  __shared__ float As[16 * 132];
  __shared__ float4 Bs4[2048];
  int tid = threadIdx.x;
  int r0 = blockIdx.x * 16;
  int n0 = blockIdx.y * 64;
  int r = tid >> 4;
  int c4 = (tid & 15) << 2;
  float4 acc = make_float4(0.f, 0.f, 0.f, 0.f);
  for (int k0 = 0; k0 < 256; k0 += 128) {
    __syncthreads();
    #pragma unroll
    for (int i = 0; i < 8; ++i) {
      int idx = tid + i * 256;
      As[(idx >> 7) * 132 + (idx & 127)] =
          feat[(size_t)(r0 + (idx >> 7)) * 256 + k0 + (idx & 127)];
    }
    #pragma unroll
    for (int i = 0; i < 8; ++i) {
      int idx = tid + i * 256;
      Bs4[idx] = *(const float4*)(w1r + (size_t)(k0 + (idx >> 4)) * 1152 + n0 + ((idx & 15) << 2));
    }
    __syncthreads();
    const float* ar = As + r * 132;
    #pragma unroll 8
    for (int k = 0; k < 128; ++k) {
      float a = ar[k];
      float4 bv = Bs4[(k << 4) + (c4 >> 2)];
      acc.x = fmaf(a, bv.x, acc.x); acc.y = fmaf(a, bv.y, acc.y);
      acc.z = fmaf(a, bv.z, acc.z); acc.w = fmaf(a, bv.w, acc.w);
    }
  }
  int row = r0 + r;
  if ((row & 511) == 0) acc = make_float4(0.f, 0.f, 0.f, 0.f);
  *(float4*)(G + (size_t)row * 1152 + n0 + c4) = acc;
}

// ---------------- K2.6: Gall ----------------
__global__ __launch_bounds__(256) void gall_kernel(
    const float* __restrict__ G, float* __restrict__ Gall) {
  int idx = blockIdx.x * 256 + threadIdx.x;
  int row = idx >> 7, oc = idx & 127;
  const float* gr = G + (size_t)row * 1152 + oc;
  float s = 0.f;
  #pragma unroll
  for (int t = 0; t < 9; ++t) s += gr[t * 128];
  Gall[idx] = s;
}

// ---------------- K2.7: w2T bf16 ----------------
__global__ __launch_bounds__(256) void w2t_kernel(
    const float* __restrict__ w2, ushort* __restrict__ w2t) {
  int oc = blockIdx.x;
  for (int k = threadIdx.x; k < 1152; k += 256) {
    int tap = k >> 7, ic = k & 127;
    w2t[(size_t)oc * 1152 + k] = f2bf(w2[(size_t)oc * 1152 + ic * 9 + tap]);
  }
}

// ---------------- K3: conv1 gather + BN1 + ReLU -> buf1 (bf16 NHWC) ----------------
// buf1: [(SR+2) rows][512 w][128 ic] bf16 ; row i <-> global h = hstart + i
__global__ __launch_bounds__(256) void conv1_gather_kernel(
    const int* __restrict__ winner,
    const float* __restrict__ G, const float* __restrict__ Gall,
    const float* __restrict__ cb, const float* __restrict__ g,
    const float* __restrict__ bt, const float* __restrict__ m,
    const float* __restrict__ v,
    ushort* __restrict__ buf1, size_t bstride, int b0, int hstart) {
  __shared__ float sscl[128], sshf[128];
  int tid = threadIdx.x;
  if (tid < 128) {
    float s = g[tid] * rsqrtf(v[tid] + 1e-5f);
    sscl[tid] = s;
    sshf[tid] = (cb[tid] - m[tid]) * s + bt[tid];
  }
  __syncthreads();
  int b = b0 + blockIdx.z;
  int px = blockIdx.x * 256 + tid;
  int r = px >> 9, w = px & 511;
  int h = hstart + r;
  ushort* dst = buf1 + (size_t)blockIdx.z * bstride + (size_t)px * 128;
  if (h < 0 || h >= HH) {
    uint4 z = make_uint4(0, 0, 0, 0);
    #pragma unroll
    for (int j = 0; j < 16; ++j) *(uint4*)(dst + j * 8) = z;
    return;
  }
  const int* wb = winner + (b << 18);
  int win[9];
  #pragma unroll
  for (int ky = 0; ky < 3; ++ky)
    #pragma unroll
    for (int kx = 0; kx < 3; ++kx) {
      int hp = h - 1 + ky, wp = w - 1 + kx;
      int s = 0;
      if (hp >= 0 && hp < HH && wp >= 0 && wp < WW) s = wb[(hp << 9) + wp];
      win[ky * 3 + kx] = s;
    }
  bool alleq = true;
  #pragma unroll
  for (int t = 1; t < 9; ++t) alleq = alleq && (win[t] == win[0]);

  if (alleq) {
    const float4* gp = (const float4*)(Gall + ((((size_t)b << 9) + win[0]) << 7));
    #pragma unroll
    for (int o8 = 0; o8 < 16; ++o8) {
      float4 a0 = gp[o8 * 2], a1 = gp[o8 * 2 + 1];
      const float* sc = &sscl[o8 * 8];
      const float* sh = &sshf[o8 * 8];
      union { ushort us[8]; uint4 v4; } pk;
      pk.us[0] = f2bf(fmaxf(fmaf(a0.x, sc[0], sh[0]), 0.f));
      pk.us[1] = f2bf(fmaxf(fmaf(a0.y, sc[1], sh[1]), 0.f));
      pk.us[2] = f2bf(fmaxf(fmaf(a0.z, sc[2], sh[2]), 0.f));
      pk.us[3] = f2bf(fmaxf(fmaf(a0.w, sc[3], sh[3]), 0.f));
      pk.us[4] = f2bf(fmaxf(fmaf(a1.x, sc[4], sh[4]), 0.f));
      pk.us[5] = f2bf(fmaxf(fmaf(a1.y, sc[5], sh[5]), 0.f));
      pk.us[6] = f2bf(fmaxf(fmaf(a1.z, sc[6], sh[6]), 0.f));
      pk.us[7] = f2bf(fmaxf(fmaf(a1.w, sc[7], sh[7]), 0.f));
      *(uint4*)(dst + o8 * 8) = pk.v4;
    }
  } else {
    size_t off[9];
    #pragma unroll
    for (int t = 0; t < 9; ++t)
      off[t] = ((size_t)((b << 9) + win[t])) * 1152 + t * 128;
    #pragma unroll
    for (int o8 = 0; o8 < 16; ++o8) {
      float4 a0 = make_float4(0, 0, 0, 0), a1 = a0;
      #pragma unroll
      for (int t = 0; t < 9; ++t) {
        const float4* gp = (const float4*)(G + off[t] + o8 * 8);
        float4 g0 = gp[0], g1 = gp[1];
        a0.x += g0.x; a0.y += g0.y; a0.z += g0.z; a0.w += g0.w;
        a1.x += g1.x; a1.y += g1.y; a1.z += g1.z; a1.w += g1.w;
      }
      const float* sc = &sscl[o8 * 8];
      const float* sh = &sshf[o8 * 8];
      union { ushort us[8]; uint4 v4; } pk;
      pk.us[0] = f2bf(fmaxf(fmaf(a0.x, sc[0], sh[0]), 0.f));
      pk.us[1] = f2bf(fmaxf(fmaf(a0.y, sc[1], sh[1]), 0.f));
      pk.us[2] = f2bf(fmaxf(fmaf(a0.z, sc[2], sh[2]), 0.f));
      pk.us[3] = f2bf(fmaxf(fmaf(a0.w, sc[3], sh[3]), 0.f));
      pk.us[4] = f2bf(fmaxf(fmaf(a1.x, sc[4], sh[4]), 0.f));
      pk.us[5] = f2bf(fmaxf(fmaf(a1.y, sc[5], sh[5]), 0.f));
      pk.us[6] = f2bf(fmaxf(fmaf(a1.z, sc[6], sh[6]), 0.f));
      pk.us[7] = f2bf(fmaxf(fmaf(a1.w, sc[7], sh[7]), 0.f));
      *(uint4*)(dst + o8 * 8) = pk.v4;
    }
  }
}

// ---------------- K4: conv2 MFMA (implicit GEMM) + BN2 + ReLU + fused conv3 ----------------
// M=256 px (4 output rows x 64 w) x N=64 oc; 4 waves.
// WAVE = one output row (64 px) x ALL 64 oc: 4x4 fragment tile ->
// per tap 4 A-reads + 4 B-reads for 16 MFMA (2.0 MFMA/ds_read).
__global__ __launch_bounds__(256) void conv2_mfma_kernel(
    const ushort* __restrict__ buf1, const ushort* __restrict__ w2t,
    const float* __restrict__ cb, const float* __restrict__ g,
    const float* __restrict__ bt, const float* __restrict__ m_,
    const float* __restrict__ v_,
    const float* __restrict__ w3, const float* __restrict__ b3,
    float* __restrict__ out, size_t bstride, int b0, int hs0, int SR) {
  __shared__ uint4 lds4[4035];              // 64560 B
  char* smem = (char*)lds4;
  int tid = threadIdx.x;
  int w0 = blockIdx.x * 64;
  int oh0 = blockIdx.y * 4;                 // 4 output rows per block
  int b = b0 + blockIdx.z;
  const ushort* B1 = buf1 + (size_t)blockIdx.z * bstride;
  int wv = tid >> 6, lane = tid & 63;
  int l15 = lane & 15, l4 = lane >> 4;

  float scl[4], shf[4];
  #pragma unroll
  for (int nf = 0; nf < 4; ++nf) {
    int oc = nf * 16 + l15;
    float s = g[oc] * rsqrtf(v_[oc] + 1e-5f);
    scl[nf] = s;
    shf[nf] = (cb[oc] - m_[oc]) * s + bt[oc];
  }

  // A fragment addresses: wave's output row = wv; A-row = wv + ky
  int aaddr[4][3];
  #pragma unroll
  for (int mf = 0; mf < 4; ++mf)
    #pragma unroll
    for (int kx = 0; kx < 3; ++kx) {
      int col = mf * 16 + l15 + kx;
      aaddr[mf][kx] = wv * 4224 + (col << 6) + ((l4 << 4) ^ (((col >> 1) & 3) << 4));
    }
  int baddr[4];
  #pragma unroll
  for (int nf = 0; nf < 4; ++nf) {
    int n = nf * 16 + l15;
    baddr[nf] = LDSB + (n << 6) + ((l4 << 4) ^ (((n >> 1) & 3) << 4));
  }

  f32x4 acc[4][4];
  #pragma unroll
  for (int mf = 0; mf < 4; ++mf)
    #pragma unroll
    for (int nf = 0; nf < 4; ++nf)
      acc[mf][nf] = (f32x4){0.f, 0.f, 0.f, 0.f};

  int bn = tid >> 2, bslot = tid & 3;
  int bd = LDSB + (bn << 6) + ((bslot << 4) ^ (((bn >> 1) & 3) << 4));

  for (int chunk = 0; chunk < 4; ++chunk) {
    int ic0 = chunk * 32;
    __syncthreads();
    // ---- A stage: 6 rows x 66 cols x 4 slots = 1584 x 16B ----
    uint4 av0, av1, av2, av3, av4, av5, av6;
    int ad0, ad1, ad2, ad3, ad4, ad5, ad6 = 0;
    av6 = make_uint4(0, 0, 0, 0);
#define ADEC(II, AV, AD) { \
      int i_ = (II); int slot = i_ & 3; int q = i_ >> 2; \
      int r_ = (q * 993) >> 16; int c_ = q - r_ * 66; \
      int wg = w0 - 1 + c_; \
      AD = ((r_ * 66 + c_) << 6) + ((slot << 4) ^ (((c_ >> 1) & 3) << 4)); \
      AV = make_uint4(0, 0, 0, 0); \
      if (wg >= 0 && wg < 512) \
        AV = *(const uint4*)(B1 + ((((size_t)(oh0 + r_)) << 9) + wg) * 128 + ic0 + slot * 8); \
    }
    ADEC(tid, av0, ad0);
    ADEC(tid + 256, av1, ad1);
    ADEC(tid + 512, av2, ad2);
    ADEC(tid + 768, av3, ad3);
    ADEC(tid + 1024, av4, ad4);
    ADEC(tid + 1280, av5, ad5);
    if (tid < 48) ADEC(tid + 1536, av6, ad6);
#undef ADEC
    uint4 bv[9];
    const ushort* wsrc = w2t + (size_t)bn * 1152 + ic0 + bslot * 8;
    #pragma unroll
    for (int j = 0; j < 9; ++j) bv[j] = *(const uint4*)(wsrc + j * 128);

    *(uint4*)(smem + ad0) = av0;
    *(uint4*)(smem + ad1) = av1;
    *(uint4*)(smem + ad2) = av2;
    *(uint4*)(smem + ad3) = av3;
    *(uint4*)(smem + ad4) = av4;
    *(uint4*)(smem + ad5) = av5;
    if (tid < 48) *(uint4*)(smem + ad6) = av6;
    #pragma unroll
    for (int j = 0; j < 9; ++j) *(uint4*)(smem + bd + j * 4096) = bv[j];
    __syncthreads();

    #pragma unroll
    for (int ky = 0; ky < 3; ++ky) {
      #pragma unroll
      for (int kx = 0; kx < 3; ++kx) {
        const int tap = ky * 3 + kx;
        bf16x8 bf0 = *(const bf16x8*)(smem + baddr[0] + tap * 4096);
        bf16x8 bf1 = *(const bf16x8*)(smem + baddr[1] + tap * 4096);
        bf16x8 bf2 = *(const bf16x8*)(smem + baddr[2] + tap * 4096);
        bf16x8 bf3 = *(const bf16x8*)(smem + baddr[3] + tap * 4096);
        #pragma unroll
        for (int mf = 0; mf < 4; ++mf) {
          bf16x8 af = *(const bf16x8*)(smem + aaddr[mf][kx] + ky * 4224);
          acc[mf][0] = __builtin_amdgcn_mfma_f32_16x16x32_bf16(af, bf0, acc[mf][0], 0, 0, 0);
          acc[mf][1] = __builtin_amdgcn_mfma_f32_16x16x32_bf16(af, bf1, acc[mf][1], 0, 0, 0);
          acc[mf][2] = __builtin_amdgcn_mfma_f32_16x16x32_bf16(af, bf2, acc[mf][2], 0, 0, 0);
          acc[mf][3] = __builtin_amdgcn_mfma_f32_16x16x32_bf16(af, bf3, acc[mf][3], 0, 0, 0);
        }
      }
    }
  }

  // ---- epilogue: two 128-px halves (rows {0,1} then {2,3}); scratch [128 px][66] f32 ----
  __syncthreads();
  #pragma unroll
  for (int half = 0; half < 2; ++half) {
    if (half) __syncthreads();
    if ((wv >> 1) == half) {
      #pragma unroll
      for (int mf = 0; mf < 4; ++mf)
        #pragma unroll
        for (int nf = 0; nf < 4; ++nf)
          #pragma unroll
          for (int rr = 0; rr < 4; ++rr) {
            int px = (wv & 1) * 64 + mf * 16 + l4 * 4 + rr;   // 0..127
            int oc = nf * 16 + l15;
            float val = fmaxf(fmaf(acc[mf][nf][rr], scl[nf], shf[nf]), 0.f);
            *(float*)(smem + (px * 66 + oc) * 4) = val;
          }
    }
    if (half == 0 && tid >= 128) {
      int idx = tid - 128;
      #pragma unroll
      for (int j = 0; j < 2; ++j) {
        int ii = idx + j * 128;
        if (ii < 144) *(uint4*)(smem + W3_OFF + ii * 16) = *(const uint4*)(w3 + ii * 4);
      }
      if (idx < NC) *(float*)(smem + B3_OFF + idx * 4) = b3[idx];
    }
    __syncthreads();
    if (tid < 128) {
      const float* w3f = (const float*)(smem + W3_OFF);
      const float* b3f = (const float*)(smem + B3_OFF);
      float a9[NC];
      #pragma unroll
      for (int c = 0; c < NC; ++c) a9[c] = b3f[c];
      #pragma unroll 8
      for (int j = 0; j < 32; ++j) {
        float2 xv = *(const float2*)(smem + (tid * 66 + 2 * j) * 4);
        #pragma unroll
        for (int c = 0; c < NC; ++c)
          a9[c] = fmaf(xv.x, w3f[c * 64 + 2 * j], fmaf(xv.y, w3f[c * 64 + 2 * j + 1], a9[c]));
      }
      int h = hs0 + oh0 + half * 2 + (tid >> 6);
      int w = w0 + (tid & 63);
      size_t base = ((size_t)b * NC) * 262144 + (size_t)h * 512 + w;
      #pragma unroll
      for (int c = 0; c < NC; ++c) out[base + (size_t)c * 262144] = a9[c];
    }
  }
}

extern "C" void kernel_launch(void* const* d_in, const int* in_sizes, int n_in,
                              void* d_out, int out_size, void* d_ws, size_t ws_size,
                              hipStream_t stream) {
  const float* hs  = (const float*)d_in[0];
  const int* bbox  = (const int*)d_in[1];
  const int* amask = (const int*)d_in[2];
  const float* pw  = (const float*)d_in[3];
  const float* pb  = (const float*)d_in[4];
  const float* w1  = (const float*)d_in[5];
  const float* c1b = (const float*)d_in[6];
  const float* g1  = (const float*)d_in[7];
  const float* b1  = (const float*)d_in[8];
  const float* m1  = (const float*)d_in[9];
  const float* v1  = (const float*)d_in[10];
  const float* w2  = (const float*)d_in[11];
  const float* c2b = (const float*)d_in[12];
  const float* g2  = (const float*)d_in[13];
  const float* b2  = (const float*)d_in[14];
  const float* m2  = (const float*)d_in[15];
  const float* v2  = (const float*)d_in[16];
  const float* w3  = (const float*)d_in[17];
  const float* b3  = (const float*)d_in[18];
  float* out = (float*)d_out;

  char* wsb = (char*)d_ws;
  float*  feat   = (float*)(wsb + 0);             // 1 MB
  int*    winner = (int*)(wsb + 1048576);         // 2 MB
  float*  G      = (float*)(wsb + 3145728);       // 4.5 MB
  float*  Gall   = (float*)(wsb + 7864320);       // 0.5 MB
  float*  w1r    = (float*)(wsb + 8388608);       // 1.18 MB
  ushort* w2t    = (ushort*)(wsb + 10485760);     // 144 KB
  ushort* buf1   = (ushort*)(wsb + 10747904);

  int SR = 512;
  while (SR > 32) {
    if (10747904 + (size_t)(SR + 2) * 131072 <= ws_size) break;
    SR >>= 1;
  }
  size_t b1s = (size_t)(SR + 2) * 65536;   // elems per batch
  int NB = (SR == 512 && ws_size >= 10747904 + 4 * b1s) ? 2 : 1;

  hipMemsetAsync(winner, 0, 2097152, stream);
  proj_gemm_kernel<<<dim3(64, 4), 256, 0, stream>>>(hs, pw, pb, feat);
  scatter_kernel<<<1024, 64, 0, stream>>>(bbox, amask, winner);
  w1r_kernel<<<1152, 256, 0, stream>>>(w1, w1r);
  gtab_gemm_kernel<<<dim3(64, 18), 256, 0, stream>>>(feat, w1r, G);
  gall_kernel<<<512, 256, 0, stream>>>(G, Gall);
  w2t_kernel<<<64, 256, 0, stream>>>(w2, w2t);

  if (NB == 2) {
    conv1_gather_kernel<<<dim3((SR + 2) * 512 / 256, 1, 2), 256, 0, stream>>>(
        winner, G, Gall, c1b, g1, b1, m1, v1, buf1, b1s, 0, -1);
    conv2_mfma_kernel<<<dim3(8, SR / 4, 2), 256, 0, stream>>>(
        buf1, w2t, c2b, g2, b2, m2, v2, w3, b3, out, b1s, 0, 0, SR);
  } else {
    int nstripes = 512 / SR;
    for (int b = 0; b < 2; ++b) {
      for (int s = 0; s < nstripes; ++s) {
        int hs0 = s * SR;
        conv1_gather_kernel<<<dim3((SR + 2) * 512 / 256, 1, 1), 256, 0, stream>>>(
            winner, G, Gall, c1b, g1, b1, m1, v1, buf1, (size_t)0, b, hs0 - 1);
        conv2_mfma_kernel<<<dim3(8, SR / 4, 1), 256, 0, stream>>>(
            buf1, w2t, c2b, g2, b2, m2, v2, w3, b3, out, (size_t)0, b, hs0, SR);
      }
    }
  }
}